// Round 5
// baseline (53.432 us; speedup 1.0000x reference)
//
#include <hip/hip_runtime.h>

// TemporalDenoise: bidirectional per-channel EMA, averaged.
// R5: R4 structure (LDS-staged (b, 32ch, 256t)+halo tiles) with
//  (1) 256-thread blocks, LCH=8 -> 16 waves/CU (was 8), to fill the HBM pipe
//  (2) corrected XOR swizzle (s>>3)&7: chunk spacing is now 8 slots, so the
//      8 ch values in a wave get 8 DISTINCT xors -> conflict-free ds_read_b128
//      (R4's (s>>3) with 16-slot spacing collided ch with ch+4 -> 5.1M cycles)
// Plain stores (nt stores cost +25% WRITE_SIZE, R3). Halo 24: 0.7^24 ~ 1.9e-4.
// Clamped staging makes t=0 / t=T-1 exact (EMA over repeated x[0] is x[0]).

#define BB 32
#define TT 2048
#define CGALL 128          // f32x4 groups per (b,t) row (512 ch)
#define CGT 8              // f32x4 groups per block = 32 ch = 128B per t
#define NCGT (CGALL / CGT) // 16
#define TB 256             // output time steps per block
#define HALO 24
#define SLOTS (TB + 2 * HALO)  // 304
#define LCH 8                  // time steps per thread
#define NCHB (TB / LCH)        // 32 chunks
#define NTHREADS (NCHB * CGT)  // 256 threads = 4 waves
#define NTB (TT / TB)          // 8 time tiles

typedef float f32x4 __attribute__((ext_vector_type(4)));

static __device__ __forceinline__ void ema4(f32x4& c, const f32x4 v,
                                            const f32x4 a, const f32x4 d) {
  c.x = fmaf(a.x, v.x, d.x * c.x);
  c.y = fmaf(a.y, v.y, d.y * c.y);
  c.z = fmaf(a.z, v.z, d.z * c.z);
  c.w = fmaf(a.w, v.w, d.w * c.w);
}

// conflict-free for LCH=8: scan lanes have s = 8*ch + const, so (s>>3)&7
// = (ch + const)&7 -> 8 distinct xors across the wave's 8 ch values.
static __device__ __forceinline__ int swz(int s, int g) {
  return s * CGT + (g ^ ((s >> 3) & 7));
}

__global__ __launch_bounds__(NTHREADS, 4) void ema_bidir_kernel(
    const f32x4* __restrict__ x, const f32x4* __restrict__ alogit4,
    f32x4* __restrict__ out) {
  __shared__ f32x4 tile[SLOTS * CGT];  // 38912 B -> 4 blocks/CU

  const int bid = blockIdx.x;
  const int tb = bid & (NTB - 1);           // time tile
  const int cgt = (bid >> 3) & (NCGT - 1);  // channel tile
  const int b = bid >> 7;                   // batch

  const int tid = threadIdx.x;
  const int cgi = tid & (CGT - 1);  // 0..7  channel group within tile
  const int ch = tid >> 3;          // 0..31 time chunk within tile

  const int tile_t0 = tb * TB;
  const f32x4* xb = x + ((size_t)b * TT) * CGALL + cgt * CGT;
  f32x4* ob = out + ((size_t)b * TT) * CGALL + cgt * CGT;

  // ---- stage tile (+halo) into LDS: streaming, coalesced, clamped ----
#pragma unroll
  for (int k = 0; k < 10; ++k) {  // ceil(304*8/256) = 10, guarded
    const int f = tid + k * NTHREADS;
    if (f < SLOTS * CGT) {
      const int s = f >> 3, gi = f & 7;
      int t = tile_t0 - HALO + s;
      t = t < 0 ? 0 : (t > TT - 1 ? TT - 1 : t);
      tile[swz(s, gi)] = xb[(size_t)t * CGALL + gi];
    }
  }

  const f32x4 al = alogit4[cgt * CGT + cgi];
  f32x4 a, d;
  a.x = 1.0f / (1.0f + __expf(-al.x));
  a.y = 1.0f / (1.0f + __expf(-al.y));
  a.z = 1.0f / (1.0f + __expf(-al.z));
  a.w = 1.0f / (1.0f + __expf(-al.w));
  d = 1.0f - a;

  __syncthreads();

  const int s0 = HALO + ch * LCH;  // first main slot of this chunk

  // ---- warm-ups (fwd and bwd chains independent -> ILP-2) ----
  f32x4 cf = tile[swz(s0 - HALO, cgi)];
  f32x4 cb = tile[swz(s0 + LCH - 1 + HALO, cgi)];
#pragma unroll
  for (int k = 1; k < HALO; ++k) {
    ema4(cf, tile[swz(s0 - HALO + k, cgi)], a, d);
    ema4(cb, tile[swz(s0 + LCH - 1 + HALO - k, cgi)], a, d);
  }

  // ---- forward main: record chunk in registers ----
  f32x4 fr[LCH];
#pragma unroll
  for (int i = 0; i < LCH; ++i) {
    ema4(cf, tile[swz(s0 + i, cgi)], a, d);
    fr[i] = cf;
  }

  // ---- backward main, fused averaged plain store ----
#pragma unroll
  for (int i = LCH - 1; i >= 0; --i) {
    ema4(cb, tile[swz(s0 + i, cgi)], a, d);
    f32x4 r;
    r.x = 0.5f * (fr[i].x + cb.x);
    r.y = 0.5f * (fr[i].y + cb.y);
    r.z = 0.5f * (fr[i].z + cb.z);
    r.w = 0.5f * (fr[i].w + cb.w);
    ob[(size_t)(tile_t0 + ch * LCH + i) * CGALL + cgi] = r;
  }
}

extern "C" void kernel_launch(void* const* d_in, const int* in_sizes, int n_in,
                              void* d_out, int out_size, void* d_ws,
                              size_t ws_size, hipStream_t stream) {
  const f32x4* x = (const f32x4*)d_in[0];
  const f32x4* alogit4 = (const f32x4*)d_in[1];
  f32x4* out = (f32x4*)d_out;

  const int grid = BB * NCGT * NTB;  // 4096 blocks x 256 threads
  ema_bidir_kernel<<<grid, NTHREADS, 0, stream>>>(x, alogit4, out);
}

// Round 6
// 48.880 us; speedup vs baseline: 1.0931x; 1.0931x over previous
//
#include <hip/hip_runtime.h>

// TemporalDenoise: bidirectional per-channel EMA, averaged.
// R6: R4/R5 LDS-staged structure, tuned per counter evidence:
//  - LCH=16, HALO=16, 128-thread blocks: 4 ds_read_b128 per output (R5 had 8),
//    warm-up fma chains per output cut 3x. 36.9KB LDS -> 4 blocks/CU, 8 waves.
//  - global_load_lds staging (fire-and-forget, no VGPR round trip). LDS dest
//    is wave-linear (required); the XOR swizzle is applied to the GLOBAL
//    source address instead (rule: swizzle both sides via source permutation).
//  - bid order: cgt fastest (consecutive blocks fetch disjoint contiguous
//    lines), tb stride 16 (tb-neighbors share an XCD -> halo L2 reuse).
// Plain stores (nt stores cost +25% WRITE_SIZE, R3). Halo 16: 0.7^16~3.3e-3
// carry decay -> ~1e-2 worst-case, threshold 5.06e-2. Clamped staging makes
// t=0 / t=T-1 exact (EMA over repeated x[0] is x[0], matches ref init).

#define BB 32
#define TT 2048
#define CGALL 128              // f32x4 groups per (b,t) row (512 ch)
#define CGT 8                  // f32x4 groups per block = 32 ch = 128B per t
#define NCGT (CGALL / CGT)     // 16
#define TB 256                 // output time steps per block
#define HALO 16
#define SLOTS (TB + 2 * HALO)  // 288
#define LCH 16                 // time steps per thread
#define NCHB (TB / LCH)        // 16 chunks
#define NTHREADS (NCHB * CGT)  // 128 threads = 2 waves
#define NTB (TT / TB)          // 8 time tiles
#define STAGE_ITERS ((SLOTS * CGT) / NTHREADS)  // 18, exact

typedef float f32x4 __attribute__((ext_vector_type(4)));
typedef __attribute__((address_space(3))) unsigned int lds_uint;
typedef const __attribute__((address_space(1))) unsigned int glob_uint;

static __device__ __forceinline__ void ema4(f32x4& c, const f32x4 v,
                                            const f32x4 a, const f32x4 d) {
  c.x = fmaf(a.x, v.x, d.x * c.x);
  c.y = fmaf(a.y, v.y, d.y * c.y);
  c.z = fmaf(a.z, v.z, d.z * c.z);
  c.w = fmaf(a.w, v.w, d.w * c.w);
}

// LDS index swizzle: slot s, group g -> s*8 + (g ^ ((s>>3)&7)).
// Within any 8 consecutive lanes of a scan read (fixed s), g spans 0..7 ->
// 8 distinct 16B sub-slots. Staging keeps LDS linear and permutes the SOURCE.
static __device__ __forceinline__ int swz(int s, int g) {
  return s * CGT + (g ^ ((s >> 3) & 7));
}

__global__ __launch_bounds__(NTHREADS, 2) void ema_bidir_kernel(
    const f32x4* __restrict__ x, const f32x4* __restrict__ alogit4,
    f32x4* __restrict__ out) {
  __shared__ f32x4 tile[SLOTS * CGT];  // 36864 B -> 4 blocks/CU

  const int bid = blockIdx.x;
  const int cgt = bid & (NCGT - 1);        // channel tile (fastest)
  const int tb = (bid >> 4) & (NTB - 1);   // time tile
  const int b = bid >> 7;                  // batch

  const int tid = threadIdx.x;
  const int cgi = tid & (CGT - 1);  // 0..7  channel group within tile
  const int ch = tid >> 3;          // 0..15 time chunk within tile

  const int tile_t0 = tb * TB;
  const f32x4* xb = x + ((size_t)b * TT) * CGALL + cgt * CGT;
  f32x4* ob = out + ((size_t)b * TT) * CGALL + cgt * CGT;

  // ---- stage tile (+halo) into LDS via global_load_lds ----
  // element f = tid + k*128; LDS dest &tile[f] is wave-linear (lane*16B).
  // LDS slot (s, g') must hold global element (s, g'^x(s)) so that
  // tile[swz(s,g)] == global (s,g): source address carries the XOR.
  {
    const int sb = tid >> 3;   // 0..15
    const int gp = tid & 7;
#pragma unroll
    for (int k = 0; k < STAGE_ITERS; ++k) {
      const int s = sb + 16 * k;
      int t = tile_t0 - HALO + s;
      t = t < 0 ? 0 : (t > TT - 1 ? TT - 1 : t);
      const int gsrc = gp ^ ((s >> 3) & 7);
      const f32x4* src = xb + (size_t)t * CGALL + gsrc;
      __builtin_amdgcn_global_load_lds((glob_uint*)src,
                                       (lds_uint*)&tile[tid + k * NTHREADS],
                                       16, 0, 0);
    }
  }

  // sigmoid while loads fly
  const f32x4 al = alogit4[cgt * CGT + cgi];
  f32x4 a, d;
  a.x = 1.0f / (1.0f + __expf(-al.x));
  a.y = 1.0f / (1.0f + __expf(-al.y));
  a.z = 1.0f / (1.0f + __expf(-al.z));
  a.w = 1.0f / (1.0f + __expf(-al.w));
  d = 1.0f - a;

  __syncthreads();  // drains vmcnt (global_load_lds) + barrier

  const int s0 = HALO + ch * LCH;  // first main slot of this chunk

  // ---- warm-ups (fwd and bwd chains independent -> ILP-2) ----
  f32x4 cf = tile[swz(s0 - HALO, cgi)];
  f32x4 cb = tile[swz(s0 + LCH - 1 + HALO, cgi)];
#pragma unroll
  for (int k = 1; k < HALO; ++k) {
    ema4(cf, tile[swz(s0 - HALO + k, cgi)], a, d);
    ema4(cb, tile[swz(s0 + LCH - 1 + HALO - k, cgi)], a, d);
  }

  // ---- forward main: record chunk in registers ----
  f32x4 fr[LCH];
#pragma unroll
  for (int i = 0; i < LCH; ++i) {
    ema4(cf, tile[swz(s0 + i, cgi)], a, d);
    fr[i] = cf;
  }

  // ---- backward main, fused averaged plain store ----
#pragma unroll
  for (int i = LCH - 1; i >= 0; --i) {
    ema4(cb, tile[swz(s0 + i, cgi)], a, d);
    f32x4 r;
    r.x = 0.5f * (fr[i].x + cb.x);
    r.y = 0.5f * (fr[i].y + cb.y);
    r.z = 0.5f * (fr[i].z + cb.z);
    r.w = 0.5f * (fr[i].w + cb.w);
    ob[(size_t)(tile_t0 + ch * LCH + i) * CGALL + cgi] = r;
  }
}

extern "C" void kernel_launch(void* const* d_in, const int* in_sizes, int n_in,
                              void* d_out, int out_size, void* d_ws,
                              size_t ws_size, hipStream_t stream) {
  const f32x4* x = (const f32x4*)d_in[0];
  const f32x4* alogit4 = (const f32x4*)d_in[1];
  f32x4* out = (f32x4*)d_out;

  const int grid = BB * NCGT * NTB;  // 4096 blocks x 128 threads
  ema_bidir_kernel<<<grid, NTHREADS, 0, stream>>>(x, alogit4, out);
}

// Round 7
// 46.491 us; speedup vs baseline: 1.1493x; 1.0514x over previous
//
#include <hip/hip_runtime.h>

// TemporalDenoise: bidirectional per-channel EMA, averaged.
// R7: barrier-free wave-private tiles.
//  - 1-wave blocks (64 thr). Each wave stages its OWN (b, 32ch, 128t)+16halo
//    tile (160 slots = 20KB LDS -> 8 blocks/CU) via global_load_lds and reads
//    only its own data => NO __syncthreads anywhere, just s_waitcnt vmcnt(N).
//    Waves free-run through stage/compute/store -> no block-wide drain bubbles.
//  - Counted vmcnt: vmcnt(2) covers slots 0..143 (all fwd reads, in-order
//    retire) -> fwd runs while the last 2 loads fly; vmcnt(0) before bwd.
//  - xi[] register save during fwd main -> bwd main needs no LDS reads
//    (48 ds_read_b128/thread, was 64).
//  - Latin-square swizzle x(s)=(s>>4)&7 (matches LCH=16 slot spacing: distinct
//    XOR across ch AND cgi in every 8-lane group), applied to the GLOBAL
//    source address; LDS dest stays linear (global_load_lds requirement).
// Plain stores (nt stores cost +25% WRITE_SIZE, R3). HALO=16: 0.7^16~3.3e-3
// decay, threshold 5.06e-2. Clamped staging makes t=0 / t=T-1 exact.

#define BB 32
#define TT 2048
#define CGALL 128              // f32x4 groups per (b,t) row (512 ch)
#define CGT 8                  // f32x4 groups per tile = 32 ch = 128B per t
#define NCGT (CGALL / CGT)     // 16
#define TB 128                 // output time steps per wave
#define HALO 16
#define SLOTS (TB + 2 * HALO)  // 160
#define LCH 16                 // time steps per thread
#define NTB (TT / TB)          // 16 time tiles
#define NTHREADS 64
#define STAGE_ITERS ((SLOTS * CGT) / NTHREADS)  // 20

typedef float f32x4 __attribute__((ext_vector_type(4)));
typedef __attribute__((address_space(3))) unsigned int lds_uint;
typedef const __attribute__((address_space(1))) unsigned int glob_uint;

static __device__ __forceinline__ void ema4(f32x4& c, const f32x4 v,
                                            const f32x4 a, const f32x4 d) {
  c.x = fmaf(a.x, v.x, d.x * c.x);
  c.y = fmaf(a.y, v.y, d.y * c.y);
  c.z = fmaf(a.z, v.z, d.z * c.z);
  c.w = fmaf(a.w, v.w, d.w * c.w);
}

// LDS element index for logical (slot s, group g).
static __device__ __forceinline__ int swz(int s, int g) {
  return s * CGT + (g ^ ((s >> 4) & 7));
}

__global__ __launch_bounds__(NTHREADS, 2) void ema_bidir_kernel(
    const f32x4* __restrict__ x, const f32x4* __restrict__ alogit4,
    f32x4* __restrict__ out) {
  __shared__ f32x4 tile[SLOTS * CGT];  // 20480 B -> 8 blocks/CU

  const int bid = blockIdx.x;
  const int cgt = bid & (NCGT - 1);        // channel tile (fastest)
  const int tb = (bid >> 4) & (NTB - 1);   // time tile
  const int b = bid >> 8;                  // batch

  const int tid = threadIdx.x;
  const int cgi = tid & (CGT - 1);  // 0..7 channel group
  const int ch = tid >> 3;          // 0..7 time chunk

  const int tile_t0 = tb * TB;
  const f32x4* xb = x + ((size_t)b * TT) * CGALL + cgt * CGT;
  f32x4* ob = out + ((size_t)b * TT) * CGALL + cgt * CGT;

  // ---- stage wave-private tile via global_load_lds ----
  // dest element tid + 64k = (slot s = (tid>>3)+8k, slot-group gp = tid&7);
  // source carries the XOR so that tile[swz(s,g)] == global (s,g).
  {
    const int sb = tid >> 3;
    const int gp = tid & 7;
#pragma unroll
    for (int k = 0; k < STAGE_ITERS; ++k) {
      const int s = sb + 8 * k;
      int t = tile_t0 - HALO + s;
      t = t < 0 ? 0 : (t > TT - 1 ? TT - 1 : t);
      const int gsrc = gp ^ ((k >> 1) & 7);  // == gp ^ ((s>>4)&7), uniform/k
      const f32x4* src = xb + (size_t)t * CGALL + gsrc;
      __builtin_amdgcn_global_load_lds((glob_uint*)src,
                                       (lds_uint*)&tile[tid + k * NTHREADS],
                                       16, 0, 0);
    }
  }

  // sigmoid while loads fly
  const f32x4 al = alogit4[cgt * CGT + cgi];
  f32x4 a, d;
  a.x = 1.0f / (1.0f + __expf(-al.x));
  a.y = 1.0f / (1.0f + __expf(-al.y));
  a.z = 1.0f / (1.0f + __expf(-al.z));
  a.w = 1.0f / (1.0f + __expf(-al.w));
  d = 1.0f - a;

  const int s0 = HALO + ch * LCH;  // first main slot of this chunk

  // wait for k=0..17 (slots 0..143): everything the fwd pass touches
  asm volatile("s_waitcnt vmcnt(2)" ::: "memory");
  __builtin_amdgcn_sched_barrier(0);

  // ---- forward: warm-up + main (save raw x into xi, results into fr) ----
  f32x4 cf = tile[swz(s0 - HALO, cgi)];
#pragma unroll
  for (int k = 1; k < HALO; ++k) {
    ema4(cf, tile[swz(s0 - HALO + k, cgi)], a, d);
  }
  f32x4 xi[LCH], fr[LCH];
#pragma unroll
  for (int i = 0; i < LCH; ++i) {
    xi[i] = tile[swz(s0 + i, cgi)];
    ema4(cf, xi[i], a, d);
    fr[i] = cf;
  }

  // wait for the remaining loads (slots 144..159): bwd warm-up territory
  asm volatile("s_waitcnt vmcnt(0)" ::: "memory");
  __builtin_amdgcn_sched_barrier(0);

  // ---- backward: warm-up from LDS, main from xi[], fused store ----
  f32x4 cb = tile[swz(s0 + LCH - 1 + HALO, cgi)];
#pragma unroll
  for (int k = 1; k < HALO; ++k) {
    ema4(cb, tile[swz(s0 + LCH - 1 + HALO - k, cgi)], a, d);
  }
#pragma unroll
  for (int i = LCH - 1; i >= 0; --i) {
    ema4(cb, xi[i], a, d);
    f32x4 r;
    r.x = 0.5f * (fr[i].x + cb.x);
    r.y = 0.5f * (fr[i].y + cb.y);
    r.z = 0.5f * (fr[i].z + cb.z);
    r.w = 0.5f * (fr[i].w + cb.w);
    ob[(size_t)(tile_t0 + ch * LCH + i) * CGALL + cgi] = r;
  }
}

extern "C" void kernel_launch(void* const* d_in, const int* in_sizes, int n_in,
                              void* d_out, int out_size, void* d_ws,
                              size_t ws_size, hipStream_t stream) {
  const f32x4* x = (const f32x4*)d_in[0];
  const f32x4* alogit4 = (const f32x4*)d_in[1];
  f32x4* out = (f32x4*)d_out;

  const int grid = BB * NCGT * NTB;  // 8192 blocks x 64 threads
  ema_bidir_kernel<<<grid, NTHREADS, 0, stream>>>(x, alogit4, out);
}